// Round 22
// baseline (283.761 us; speedup 1.0000x reference)
//
#include <hip/hip_runtime.h>
#include <hip/hip_bf16.h>
#include <math.h>

#define N_NODES 80000
#define N_EDGES 640000
#define B_GR 800
#define NPG 100
#define HID 128
#define NC 10
#define IND 20
#define BN_EPS 1e-5f
#define ENT_CAP 1024

// ---------- edge pass: dense byte-adjacency only ----------
__global__ void k_A(const int* __restrict__ src, const int* __restrict__ dst,
                    unsigned int* A) {
    int e = blockIdx.x * blockDim.x + threadIdx.x;
    if (e < N_EDGES) {
        int s = src[e], d = dst[e];
        int g = d / NPG;
        int bidx = g * (NPG * NPG) + (d - g * NPG) * NPG + (s - g * NPG);
        atomicAdd(&A[bidx >> 2], 1u << ((bidx & 3) * 8));
    }
}

// ---------- per-graph prep: degrees from A marginals + agg20 + compact entry list ----------
__global__ __launch_bounds__(128) void k_prep(const unsigned int* __restrict__ A,
                                              float* __restrict__ inv_in,
                                              float* __restrict__ inv_out,
                                              float* __restrict__ agg20,
                                              unsigned int* __restrict__ ent,
                                              int* __restrict__ goff) {
    __shared__ unsigned int s_A[NPG * 25];
    __shared__ float s_io[NPG];
    __shared__ int   s_ix[NPG];
    __shared__ float s_agg[NPG][IND + 1];
    __shared__ int s_offs[128];
    int g = blockIdx.x, gbase = g * NPG, t = threadIdx.x;
    const unsigned int* Ag = A + g * 2500;
    for (int i = t; i < NPG * 25; i += 128) s_A[i] = Ag[i];
    __syncthreads();

    int nnz = 0;
    if (t < NPG) {
        int rsum = 0;
        const unsigned int* row = &s_A[t * 25];
#pragma unroll
        for (int q = 0; q < 25; ++q) {
            unsigned int c4 = row[q];
            rsum += (int)((c4 & 255u) + ((c4 >> 8) & 255u) + ((c4 >> 16) & 255u) + (c4 >> 24));
            nnz += (int)((c4 & 255u) != 0) + (int)(((c4 >> 8) & 255u) != 0)
                 + (int)(((c4 >> 16) & 255u) != 0) + (int)((c4 >> 24) != 0);
        }
        int csum = 0;
        int wq = t >> 2, sh = (t & 3) * 8;
#pragma unroll 4
        for (int r = 0; r < NPG; ++r)
            csum += (int)((s_A[r * 25 + wq] >> sh) & 255u);

        float io = rsqrtf(fmaxf((float)csum, 1.f));
        inv_in[gbase + t]  = rsqrtf(fmaxf((float)rsum, 1.f));
        inv_out[gbase + t] = io;
        s_io[t] = io;
        s_ix[t] = rsum > IND - 1 ? IND - 1 : rsum;
    }
    int v = nnz;
    s_offs[t] = v;
    __syncthreads();
    for (int d = 1; d < 128; d <<= 1) {
        int x = (t >= d) ? s_offs[t - d] : 0;
        __syncthreads();
        s_offs[t] += x;
        __syncthreads();
    }
    int my_off = s_offs[t] - v;
    if (t < NPG) goff[g * 104 + t] = my_off;
    if (t == 0) goff[g * 104 + NPG] = s_offs[127];
    __syncthreads();

    if (t < NPG) {
#pragma unroll
        for (int k = 0; k < IND; ++k) s_agg[t][k] = 0.f;
        const unsigned int* row = &s_A[t * 25];
        unsigned int* ep = ent + (size_t)g * ENT_CAP + my_off;
        int w = 0;
#pragma unroll
        for (int q = 0; q < 25; ++q) {
            unsigned int c4 = row[q];
            if (c4 == 0) continue;
#pragma unroll
            for (int b = 0; b < 4; ++b) {
                unsigned int cnt = (c4 >> (8 * b)) & 255u;
                if (cnt) {
                    int s = q * 4 + b;
                    s_agg[t][s_ix[s]] += (float)cnt * s_io[s];
                    ep[w++] = ((unsigned int)s << 8) | cnt;
                }
            }
        }
        float* outp = agg20 + (size_t)(gbase + t) * IND;
#pragma unroll
        for (int k = 0; k < IND; ++k) outp[k] = s_agg[t][k];
    }
}

// ---------- BN1 stats via moments ----------
#define MOM_CHUNK 64
__global__ __launch_bounds__(256) void k_mom(const float* __restrict__ agg20,
                                             const float* __restrict__ inv_in,
                                             float* s20, float* Mbuf) {
    __shared__ float rows[MOM_CHUNK * IND];
    __shared__ float w1s[MOM_CHUNK], w2s[MOM_CHUNK];
    int t = threadIdx.x;
    int k = 0, l = 0;
    bool isM = (t < 210), isS = (t >= 210 && t < 230);
    if (isM) {
        int idx = t, kk = 0;
        while (idx >= IND - kk) { idx -= IND - kk; ++kk; }
        k = kk; l = kk + idx;
    } else if (isS) {
        k = t - 210;
    }
    float acc = 0.f;
    for (int c = blockIdx.x; c < N_NODES / MOM_CHUNK; c += gridDim.x) {
        __syncthreads();
        for (int i = t * 4; i < MOM_CHUNK * IND; i += 1024)
            *(float4*)&rows[i] = *(const float4*)&agg20[(size_t)c * MOM_CHUNK * IND + i];
        if (t < MOM_CHUNK) {
            float v = inv_in[c * MOM_CHUNK + t];
            w1s[t] = v; w2s[t] = v * v;
        }
        __syncthreads();
        if (isM) {
            for (int i = 0; i < MOM_CHUNK; ++i)
                acc += w2s[i] * rows[i * IND + k] * rows[i * IND + l];
        } else if (isS) {
            for (int i = 0; i < MOM_CHUNK; ++i)
                acc += w1s[i] * rows[i * IND + k];
        }
    }
    if (isM) atomicAdd(&Mbuf[t], acc);
    else if (isS) atomicAdd(&s20[t - 210], acc);
}

// a1,c1 from moments
__global__ void k_bn1fin(const float* __restrict__ s20, const float* __restrict__ Mbuf,
                         const float* __restrict__ W1, const float* __restrict__ b1,
                         const float* __restrict__ g1, const float* __restrict__ be1,
                         float* a1, float* c1) {
    __shared__ float sM[210], ss[IND];
    int j = threadIdx.x;
    if (j < 210) sM[j] = Mbuf[j];
    if (j + 128 < 210) sM[j + 128] = Mbuf[j + 128];
    if (j < IND) ss[j] = s20[j];
    __syncthreads();
    float w[IND];
#pragma unroll
    for (int k = 0; k < IND; ++k) w[k] = W1[k * HID + j];
    float tj = 0.f;
#pragma unroll
    for (int k = 0; k < IND; ++k) tj += ss[k] * w[k];
    float q = 0.f;
    int idx = 0;
#pragma unroll
    for (int k = 0; k < IND; ++k) {
        q += sM[idx] * w[k] * w[k]; ++idx;
#pragma unroll
        for (int l = k + 1; l < IND; ++l) { q += 2.f * sM[idx] * w[k] * w[l]; ++idx; }
    }
    float bj = b1[j];
    const float Nf = (float)N_NODES;
    float mean = (tj + Nf * bj) / Nf;
    float ey2  = (q + 2.f * bj * tj + Nf * bj * bj) / Nf;
    float var  = ey2 - mean * mean;
    float aj = g1[j] / sqrtf(var + BN_EPS);
    a1[j] = aj;
    c1[j] = be1[j] - mean * aj;
}

// ---------- fused layer 1: h1s = elu(bn(inv_in*(agg20@W1)+b1)) * inv_out ----------
__global__ __launch_bounds__(256) void k_l1f(const float* __restrict__ agg20,
                                             const float* __restrict__ inv_in,
                                             const float* __restrict__ inv_out,
                                             const float* __restrict__ W1,
                                             const float* __restrict__ b1,
                                             const float* __restrict__ a1,
                                             const float* __restrict__ c1,
                                             float* __restrict__ h1s) {
    __shared__ float ws[IND * HID];   // 10 KB
    int t = threadIdx.x;
    for (int i = t * 4; i < IND * HID; i += 1024)
        *(float4*)&ws[i] = *(const float4*)&W1[i];
    __syncthreads();
    int tx = t & 15, ty = t >> 4;
    int c0 = tx * 8;
    float4 ba = *(const float4*)(b1 + c0);
    float4 bb = *(const float4*)(b1 + c0 + 4);
    float4 aa = *(const float4*)(a1 + c0);
    float4 ab = *(const float4*)(a1 + c0 + 4);
    float4 ca = *(const float4*)(c1 + c0);
    float4 cb = *(const float4*)(c1 + c0 + 4);

    int row0 = blockIdx.x * 64 + ty * 4;
    const float* xr0 = agg20 + (size_t)row0 * IND;
    const float* xr1 = xr0 + IND;
    const float* xr2 = xr1 + IND;
    const float* xr3 = xr2 + IND;
    float acc[4][8];
#pragma unroll
    for (int r = 0; r < 4; ++r)
#pragma unroll
        for (int c = 0; c < 8; ++c) acc[r][c] = 0.f;

#pragma unroll
    for (int k = 0; k < IND; k += 4) {
        float4 x0 = *(const float4*)(xr0 + k);
        float4 x1 = *(const float4*)(xr1 + k);
        float4 x2 = *(const float4*)(xr2 + k);
        float4 x3 = *(const float4*)(xr3 + k);
#pragma unroll
        for (int kk = 0; kk < 4; ++kk) {
            float4 wa = *(const float4*)&ws[(k + kk) * HID + c0];
            float4 wb = *(const float4*)&ws[(k + kk) * HID + c0 + 4];
            float xk0 = (kk == 0) ? x0.x : (kk == 1) ? x0.y : (kk == 2) ? x0.z : x0.w;
            float xk1 = (kk == 0) ? x1.x : (kk == 1) ? x1.y : (kk == 2) ? x1.z : x1.w;
            float xk2 = (kk == 0) ? x2.x : (kk == 1) ? x2.y : (kk == 2) ? x2.z : x2.w;
            float xk3 = (kk == 0) ? x3.x : (kk == 1) ? x3.y : (kk == 2) ? x3.z : x3.w;
            acc[0][0] += xk0 * wa.x; acc[0][1] += xk0 * wa.y;
            acc[0][2] += xk0 * wa.z; acc[0][3] += xk0 * wa.w;
            acc[0][4] += xk0 * wb.x; acc[0][5] += xk0 * wb.y;
            acc[0][6] += xk0 * wb.z; acc[0][7] += xk0 * wb.w;
            acc[1][0] += xk1 * wa.x; acc[1][1] += xk1 * wa.y;
            acc[1][2] += xk1 * wa.z; acc[1][3] += xk1 * wa.w;
            acc[1][4] += xk1 * wb.x; acc[1][5] += xk1 * wb.y;
            acc[1][6] += xk1 * wb.z; acc[1][7] += xk1 * wb.w;
            acc[2][0] += xk2 * wa.x; acc[2][1] += xk2 * wa.y;
            acc[2][2] += xk2 * wa.z; acc[2][3] += xk2 * wa.w;
            acc[2][4] += xk2 * wb.x; acc[2][5] += xk2 * wb.y;
            acc[2][6] += xk2 * wb.z; acc[2][7] += xk2 * wb.w;
            acc[3][0] += xk3 * wa.x; acc[3][1] += xk3 * wa.y;
            acc[3][2] += xk3 * wa.z; acc[3][3] += xk3 * wa.w;
            acc[3][4] += xk3 * wb.x; acc[3][5] += xk3 * wb.y;
            acc[3][6] += xk3 * wb.z; acc[3][7] += xk3 * wb.w;
        }
    }
    float4 iv = *(const float4*)(inv_in + row0);
    float4 ov = *(const float4*)(inv_out + row0);
#pragma unroll
    for (int r = 0; r < 4; ++r) {
        float ivr = (r == 0) ? iv.x : (r == 1) ? iv.y : (r == 2) ? iv.z : iv.w;
        float ovr = (r == 0) ? ov.x : (r == 1) ? ov.y : (r == 2) ? ov.z : ov.w;
        float y[8];
        y[0] = acc[r][0] * ivr + ba.x; y[1] = acc[r][1] * ivr + ba.y;
        y[2] = acc[r][2] * ivr + ba.z; y[3] = acc[r][3] * ivr + ba.w;
        y[4] = acc[r][4] * ivr + bb.x; y[5] = acc[r][5] * ivr + bb.y;
        y[6] = acc[r][6] * ivr + bb.z; y[7] = acc[r][7] * ivr + bb.w;
        float z[8];
        z[0] = y[0] * aa.x + ca.x; z[1] = y[1] * aa.y + ca.y;
        z[2] = y[2] * aa.z + ca.z; z[3] = y[3] * aa.w + ca.w;
        z[4] = y[4] * ab.x + cb.x; z[5] = y[5] * ab.y + cb.y;
        z[6] = y[6] * ab.z + cb.z; z[7] = y[7] * ab.w + cb.w;
#pragma unroll
        for (int c = 0; c < 8; ++c) {
            float h = z[c] > 0.f ? z[c] : expm1f(z[c]);
            z[c] = h * ovr;
        }
        float* yr = h1s + (size_t)(row0 + r) * HID + c0;
        *(float4*)yr = make_float4(z[0], z[1], z[2], z[3]);
        *(float4*)(yr + 4) = make_float4(z[4], z[5], z[6], z[7]);
    }
}

// ---------- fused gather + GEMM: per graph; agg2 never touches HBM ----------
// Phase A: stage h1 slice -> LDS.  Phase B: entry-list gather -> registers.
// Phase C: overwrite LDS with agg2.  Phase D: GEMM from LDS (broadcast b128
// reads) with W2 streamed from L2; y2 out + BN stats.
__global__ __launch_bounds__(512) void k_aggemm(const unsigned int* __restrict__ ent,
                                                const int* __restrict__ goff,
                                                const float* __restrict__ h1s,
                                                const float* __restrict__ inv_in,
                                                const float* __restrict__ W2,
                                                const float* __restrict__ b2,
                                                float* __restrict__ y2,
                                                float* sums, float* sqs) {
    __shared__ float sh[NPG * HID];   // 51.2 KB -> 3 blocks/CU
    __shared__ int s_off[NPG + 1];
    int t = threadIdx.x;
    int g = blockIdx.x, gbase = g * NPG;

    // Phase A: stage h1
    const float4* srcp = (const float4*)(h1s + (size_t)gbase * HID);
    float4* shp = (float4*)sh;
    for (int i = t; i < (NPG * HID) / 4; i += 512)
        shp[i] = srcp[i];
    if (t <= NPG) s_off[t] = goff[g * 104 + t];
    __syncthreads();

    // Phase B: gather agg2 rows into registers (static indices; rows r = wv+8*i)
    int wv = t >> 6, lane = t & 63;
    const unsigned int* ep = ent + (size_t)g * ENT_CAP;
    float2 ar[13];
#pragma unroll
    for (int i = 0; i < 13; ++i) {
        int r = wv + 8 * i;
        float ax = 0.f, ay = 0.f;
        if (r < NPG) {
            int e0 = s_off[r], e1 = s_off[r + 1];
            int e = e0;
            for (; e + 8 <= e1; e += 8) {
                unsigned int ee[8];
#pragma unroll
                for (int j = 0; j < 8; ++j) ee[j] = ep[e + j];
#pragma unroll
                for (int j = 0; j < 8; ++j) {
                    float f = (float)(ee[j] & 255u);
                    int s = ee[j] >> 8;
                    float2 v = *(const float2*)&sh[s * HID + lane * 2];
                    ax += f * v.x; ay += f * v.y;
                }
            }
            for (; e < e1; ++e) {
                unsigned int eo = ep[e];
                float f = (float)(eo & 255u);
                int s = eo >> 8;
                float2 v = *(const float2*)&sh[s * HID + lane * 2];
                ax += f * v.x; ay += f * v.y;
            }
        }
        ar[i] = make_float2(ax, ay);
    }
    __syncthreads();

    // Phase C: overwrite LDS with agg2
#pragma unroll
    for (int i = 0; i < 13; ++i) {
        int r = wv + 8 * i;
        if (r < NPG)
            *(float2*)&sh[r * HID + lane * 2] = ar[i];
    }
    __syncthreads();

    // Phase D: GEMM. tx = col, ty = row-quarter (25 rows each).
    int tx = t & 127, ty = t >> 7;
    int rbase = ty * 25;
    float acc[25];
#pragma unroll
    for (int r = 0; r < 25; ++r) acc[r] = 0.f;
    for (int k = 0; k < HID; k += 4) {
        float w0 = W2[(k + 0) * HID + tx];       // coalesced in tx, L2-hot
        float w1 = W2[(k + 1) * HID + tx];
        float w2v = W2[(k + 2) * HID + tx];
        float w3 = W2[(k + 3) * HID + tx];
#pragma unroll
        for (int r = 0; r < 25; ++r) {
            float4 a = *(const float4*)&sh[(rbase + r) * HID + k];   // wave-uniform broadcast
            acc[r] += a.x * w0 + a.y * w1 + a.z * w2v + a.w * w3;
        }
    }

    float bj = b2[tx];
    float cs = 0.f, cq = 0.f;
#pragma unroll
    for (int r = 0; r < 25; ++r) {
        int row = gbase + rbase + r;
        float y = acc[r] * inv_in[row] + bj;
        y2[(size_t)row * HID + tx] = y;          // coalesced in tx
        cs += y; cq += y * y;
    }

    // column stats: reuse sh head (GEMM reads done)
    __syncthreads();
    sh[ty * HID + tx] = cs;
    sh[512 + ty * HID + tx] = cq;
    __syncthreads();
    if (t < HID) {
        float s = sh[t] + sh[HID + t] + sh[2 * HID + t] + sh[3 * HID + t];
        float q = sh[512 + t] + sh[512 + HID + t] + sh[512 + 2 * HID + t] + sh[512 + 3 * HID + t];
        atomicAdd(&sums[t], s);
        atomicAdd(&sqs[t], q);
    }
}

// ---------- BN finalize (layers 2,3) ----------
__global__ void k_bnfin(const float* sums, const float* sqs,
                        const float* gamma, const float* beta,
                        float cnt, float* a, float* c) {
    int j = threadIdx.x;
    float mu  = sums[j] / cnt;
    float var = sqs[j] / cnt - mu * mu;
    float aj  = gamma[j] / sqrtf(var + BN_EPS);
    a[j] = aj;
    c[j] = beta[j] - mu * aj;
}

// ---------- fused post: BN2+ELU in LDS + p + dvec (entry list) + pooling ----------
__global__ __launch_bounds__(512) void k_post(const unsigned int* __restrict__ ent,
                                              const int* __restrict__ goff,
                                              const float* __restrict__ y2,
                                              const float* __restrict__ a2,
                                              const float* __restrict__ c2,
                                              const float* __restrict__ inv_in,
                                              const float* __restrict__ inv_out,
                                              const float* __restrict__ Wv,
                                              const float* __restrict__ bv,
                                              float* __restrict__ vec,
                                              float* meansum) {
    __shared__ float sh[NPG * HID];
    __shared__ float s_p[NPG];
    __shared__ float s_d[NPG];
    __shared__ float s_red[512];
    __shared__ int s_off[NPG + 1];
    int t = threadIdx.x;
    int g = blockIdx.x, gbase = g * NPG;

    const float4* srcp = (const float4*)(y2 + (size_t)gbase * HID);
    for (int i = t; i < (NPG * HID) / 4; i += 512) {
        int col = (i * 4) & (HID - 1);
        float4 v = srcp[i];
        float4 av = *(const float4*)(a2 + col);
        float4 cv = *(const float4*)(c2 + col);
        float z0 = v.x * av.x + cv.x; z0 = z0 > 0.f ? z0 : expm1f(z0);
        float z1 = v.y * av.y + cv.y; z1 = z1 > 0.f ? z1 : expm1f(z1);
        float z2 = v.z * av.z + cv.z; z2 = z2 > 0.f ? z2 : expm1f(z2);
        float z3 = v.w * av.w + cv.w; z3 = z3 > 0.f ? z3 : expm1f(z3);
        *(float4*)&sh[i * 4] = make_float4(z0, z1, z2, z3);
    }
    if (t <= NPG) s_off[t] = goff[g * 104 + t];
    __syncthreads();

    int wv = t >> 6, lane = t & 63;
    float2 wvv = *(const float2*)(Wv + lane * 2);
    for (int r = wv; r < NPG; r += 8) {
        float2 h = *(const float2*)&sh[r * HID + lane * 2];
        float d = h.x * wvv.x + h.y * wvv.y;
        for (int off = 32; off; off >>= 1) d += __shfl_down(d, off);
        if (lane == 0) s_p[r] = d * inv_out[gbase + r];
    }
    __syncthreads();

    if (t < NPG) {
        const unsigned int* ep = ent + (size_t)g * ENT_CAP;
        int e0 = s_off[t], e1 = s_off[t + 1];
        float acc = 0.f;
        for (int i = e0; i < e1; ++i) {
            unsigned int e = ep[i];
            acc += (float)(e & 255u) * s_p[e >> 8];
        }
        s_d[t] = acc * inv_in[gbase + t] + bv[0];
    }
    __syncthreads();

    int col = t & (HID - 1);
    int qr = t >> 7;
    float part = 0.f;
    for (int r = qr * 25; r < qr * 25 + 25; ++r)
        part += s_d[r] * sh[r * HID + col];
    s_red[qr * HID + col] = part;
    __syncthreads();
    if (t < HID) {
        float v = s_red[t] + s_red[HID + t] + s_red[2 * HID + t] + s_red[3 * HID + t];
        vec[g * HID + t] = v;
        for (int off = 32; off; off >>= 1) v += __shfl_down(v, off);
        if ((t & 63) == 0) atomicAdd(meansum, v);
    }
}

// shrink+tanh then y3 = hg0 @ Wg + bg, fused BN stats
__global__ __launch_bounds__(128) void k_g1(const float* __restrict__ vec,
                                            const float* __restrict__ meansum,
                                            const float* __restrict__ Wg,
                                            const float* __restrict__ bg,
                                            float* y3, float* sums, float* sqs) {
    __shared__ float ws[HID * HID];
    __shared__ float rows[HID];
    int g = blockIdx.x, j = threadIdx.x;
    for (int k = 0; k < HID; ++k) ws[k * HID + j] = Wg[k * HID + j];
    float mean = meansum[0] * (1.f / (B_GR * HID));
    float v = vec[g * HID + j];
    float sh = fmaxf(v - mean, 0.f) - fmaxf(-v - mean, 0.f);
    rows[j] = tanhf(sh);
    __syncthreads();
    float acc = 0.f;
#pragma unroll 8
    for (int k = 0; k < HID; ++k) acc += rows[k] * ws[k * HID + j];
    float y = acc + bg[j];
    y3[g * HID + j] = y;
    atomicAdd(&sums[j], y);
    atomicAdd(&sqs[j], y * y);
}

// final: hg = tanh(bn(y3)), out = tanh(hg @ Wc + bc)
__global__ __launch_bounds__(128) void k_out(const float* __restrict__ y3,
                                             const float* __restrict__ a,
                                             const float* __restrict__ c,
                                             const float* __restrict__ Wc,
                                             const float* __restrict__ bc,
                                             float* out) {
    __shared__ float hg[HID];
    int g = blockIdx.x, j = threadIdx.x;
    hg[j] = tanhf(y3[g * HID + j] * a[j] + c[j]);
    __syncthreads();
    if (j < NC) {
        float acc = 0.f;
        for (int k = 0; k < HID; ++k) acc += hg[k] * Wc[k * NC + j];
        out[g * NC + j] = tanhf(acc + bc[j]);
    }
}

extern "C" void kernel_launch(void* const* d_in, const int* in_sizes, int n_in,
                              void* d_out, int out_size, void* d_ws, size_t ws_size,
                              hipStream_t stream) {
    const int*   src = (const int*)d_in[0];
    const int*   dst = (const int*)d_in[1];
    const float* W1  = (const float*)d_in[3];
    const float* b1  = (const float*)d_in[4];
    const float* g1  = (const float*)d_in[5];
    const float* be1 = (const float*)d_in[6];
    const float* W2  = (const float*)d_in[7];
    const float* b2  = (const float*)d_in[8];
    const float* g2  = (const float*)d_in[9];
    const float* be2 = (const float*)d_in[10];
    const float* Wv  = (const float*)d_in[11];
    const float* bv  = (const float*)d_in[12];
    const float* Wg  = (const float*)d_in[15];
    const float* bg  = (const float*)d_in[16];
    const float* g3  = (const float*)d_in[17];
    const float* be3 = (const float*)d_in[18];
    const float* Wc  = (const float*)d_in[19];
    const float* bc  = (const float*)d_in[20];
    float* out = (float*)d_out;

    char* ws = (char*)d_ws;
    size_t off = 0;
    auto carve = [&](size_t bytes) -> char* {
        char* pp = ws + off;
        off = (off + bytes + 255) & ~(size_t)255;
        return pp;
    };
    // ---- zeroed region ----
    unsigned int* A = (unsigned int*)carve((size_t)B_GR * NPG * NPG);  // 8 MB
    float* stats   = (float*)carve(2048 * 4);
    size_t zbytes = off;
    // ---- fully-overwritten region ----
    float* inv_in  = (float*)carve(N_NODES * 4);
    float* inv_out = (float*)carve(N_NODES * 4);
    float* vec     = (float*)carve((size_t)B_GR * HID * 4);
    float* y3      = (float*)carve((size_t)B_GR * HID * 4);
    float* agg20   = (float*)carve((size_t)N_NODES * IND * 4);
    float* bufA    = (float*)carve((size_t)N_NODES * HID * 4);   // h1s
    float* bufB    = (float*)carve((size_t)N_NODES * HID * 4);   // y2
    unsigned int* ent = (unsigned int*)carve((size_t)B_GR * ENT_CAP * 4);
    int* goff      = (int*)carve((size_t)B_GR * 104 * 4);

    float* sums2 = stats + 0;    float* sq2 = stats + 128;
    float* a2    = stats + 256;  float* c2  = stats + 384;
    float* sums3 = stats + 512;  float* sq3 = stats + 640;
    float* a3    = stats + 768;  float* c3  = stats + 896;
    float* meansum = stats + 1024;
    float* s20   = stats + 1056;
    float* Mbuf  = stats + 1088;
    float* a1    = stats + 1312;
    float* c1    = stats + 1440;

    hipMemsetAsync(d_ws, 0, zbytes, stream);

    // single edge pass: adjacency only (1 atomic/edge)
    k_A<<<(N_EDGES + 255) / 256, 256, 0, stream>>>(src, dst, A);
    // per-graph: degrees + inv + agg20 + compact entry list
    k_prep<<<B_GR, 128, 0, stream>>>(A, inv_in, inv_out, agg20, ent, goff);
    // BN1 via moments, then fused layer-1 pass
    k_mom<<<320, 256, 0, stream>>>(agg20, inv_in, s20, Mbuf);
    k_bn1fin<<<1, 128, 0, stream>>>(s20, Mbuf, W1, b1, g1, be1, a1, c1);
    k_l1f<<<N_NODES / 64, 256, 0, stream>>>(agg20, inv_in, inv_out, W1, b1, a1, c1, bufA);
    // fused layer-2 aggregation + GEMM (agg2 lives only in LDS)
    k_aggemm<<<B_GR, 512, 0, stream>>>(ent, goff, bufA, inv_in, W2, b2, bufB, sums2, sq2);
    k_bnfin<<<1, 128, 0, stream>>>(sums2, sq2, g2, be2, (float)N_NODES, a2, c2);
    // fused BN2+ELU+p+dvec+pooling
    k_post<<<B_GR, 512, 0, stream>>>(ent, goff, bufB, a2, c2, inv_in, inv_out, Wv, bv,
                                     vec, meansum);
    // graph head
    k_g1<<<B_GR, 128, 0, stream>>>(vec, meansum, Wg, bg, y3, sums3, sq3);
    k_bnfin<<<1, 128, 0, stream>>>(sums3, sq3, g3, be3, (float)B_GR, a3, c3);
    k_out<<<B_GR, 128, 0, stream>>>(y3, a3, c3, Wc, bc, out);
}

// Round 23
// 269.856 us; speedup vs baseline: 1.0515x; 1.0515x over previous
//
#include <hip/hip_runtime.h>
#include <hip/hip_bf16.h>
#include <math.h>

#define N_NODES 80000
#define N_EDGES 640000
#define B_GR 800
#define NPG 100
#define HID 128
#define NC 10
#define IND 20
#define BN_EPS 1e-5f
#define ENT_CAP 1024

// ---------- edge pass: dense byte-adjacency only (1 fire-and-forget atomic/edge) ----------
__global__ void k_A(const int* __restrict__ src, const int* __restrict__ dst,
                    unsigned int* A) {
    int e = blockIdx.x * blockDim.x + threadIdx.x;
    if (e < N_EDGES) {
        int s = src[e], d = dst[e];
        int g = d / NPG;
        int bidx = g * (NPG * NPG) + (d - g * NPG) * NPG + (s - g * NPG);
        atomicAdd(&A[bidx >> 2], 1u << ((bidx & 3) * 8));
    }
}

// ---------- per-graph prep: degrees from A marginals + agg20 + compact entry list ----------
__global__ __launch_bounds__(128) void k_prep(const unsigned int* __restrict__ A,
                                              float* __restrict__ inv_in,
                                              float* __restrict__ inv_out,
                                              float* __restrict__ agg20,
                                              unsigned int* __restrict__ ent,
                                              int* __restrict__ goff) {
    __shared__ unsigned int s_A[NPG * 25];
    __shared__ float s_io[NPG];
    __shared__ int   s_ix[NPG];
    __shared__ float s_agg[NPG][IND + 1];
    __shared__ int s_offs[128];
    int g = blockIdx.x, gbase = g * NPG, t = threadIdx.x;
    const unsigned int* Ag = A + g * 2500;
    for (int i = t; i < NPG * 25; i += 128) s_A[i] = Ag[i];
    __syncthreads();

    int nnz = 0;
    if (t < NPG) {
        int rsum = 0;
        const unsigned int* row = &s_A[t * 25];
#pragma unroll
        for (int q = 0; q < 25; ++q) {
            unsigned int c4 = row[q];
            rsum += (int)((c4 & 255u) + ((c4 >> 8) & 255u) + ((c4 >> 16) & 255u) + (c4 >> 24));
            nnz += (int)((c4 & 255u) != 0) + (int)(((c4 >> 8) & 255u) != 0)
                 + (int)(((c4 >> 16) & 255u) != 0) + (int)((c4 >> 24) != 0);
        }
        int csum = 0;
        int wq = t >> 2, sh = (t & 3) * 8;
#pragma unroll 4
        for (int r = 0; r < NPG; ++r)
            csum += (int)((s_A[r * 25 + wq] >> sh) & 255u);

        float io = rsqrtf(fmaxf((float)csum, 1.f));
        inv_in[gbase + t]  = rsqrtf(fmaxf((float)rsum, 1.f));
        inv_out[gbase + t] = io;
        s_io[t] = io;
        s_ix[t] = rsum > IND - 1 ? IND - 1 : rsum;
    }
    int v = nnz;
    s_offs[t] = v;
    __syncthreads();
    for (int d = 1; d < 128; d <<= 1) {
        int x = (t >= d) ? s_offs[t - d] : 0;
        __syncthreads();
        s_offs[t] += x;
        __syncthreads();
    }
    int my_off = s_offs[t] - v;
    if (t < NPG) goff[g * 104 + t] = my_off;
    if (t == 0) goff[g * 104 + NPG] = s_offs[127];
    __syncthreads();

    if (t < NPG) {
#pragma unroll
        for (int k = 0; k < IND; ++k) s_agg[t][k] = 0.f;
        const unsigned int* row = &s_A[t * 25];
        unsigned int* ep = ent + (size_t)g * ENT_CAP + my_off;
        int w = 0;
#pragma unroll
        for (int q = 0; q < 25; ++q) {
            unsigned int c4 = row[q];
            if (c4 == 0) continue;
#pragma unroll
            for (int b = 0; b < 4; ++b) {
                unsigned int cnt = (c4 >> (8 * b)) & 255u;
                if (cnt) {
                    int s = q * 4 + b;
                    s_agg[t][s_ix[s]] += (float)cnt * s_io[s];
                    ep[w++] = ((unsigned int)s << 8) | cnt;
                }
            }
        }
        float* outp = agg20 + (size_t)(gbase + t) * IND;
#pragma unroll
        for (int k = 0; k < IND; ++k) outp[k] = s_agg[t][k];
    }
}

// ---------- BN1 stats via moments ----------
#define MOM_CHUNK 64
__global__ __launch_bounds__(256) void k_mom(const float* __restrict__ agg20,
                                             const float* __restrict__ inv_in,
                                             float* s20, float* Mbuf) {
    __shared__ float rows[MOM_CHUNK * IND];
    __shared__ float w1s[MOM_CHUNK], w2s[MOM_CHUNK];
    int t = threadIdx.x;
    int k = 0, l = 0;
    bool isM = (t < 210), isS = (t >= 210 && t < 230);
    if (isM) {
        int idx = t, kk = 0;
        while (idx >= IND - kk) { idx -= IND - kk; ++kk; }
        k = kk; l = kk + idx;
    } else if (isS) {
        k = t - 210;
    }
    float acc = 0.f;
    for (int c = blockIdx.x; c < N_NODES / MOM_CHUNK; c += gridDim.x) {
        __syncthreads();
        for (int i = t * 4; i < MOM_CHUNK * IND; i += 1024)
            *(float4*)&rows[i] = *(const float4*)&agg20[(size_t)c * MOM_CHUNK * IND + i];
        if (t < MOM_CHUNK) {
            float v = inv_in[c * MOM_CHUNK + t];
            w1s[t] = v; w2s[t] = v * v;
        }
        __syncthreads();
        if (isM) {
            for (int i = 0; i < MOM_CHUNK; ++i)
                acc += w2s[i] * rows[i * IND + k] * rows[i * IND + l];
        } else if (isS) {
            for (int i = 0; i < MOM_CHUNK; ++i)
                acc += w1s[i] * rows[i * IND + k];
        }
    }
    if (isM) atomicAdd(&Mbuf[t], acc);
    else if (isS) atomicAdd(&s20[t - 210], acc);
}

// a1,c1 from moments
__global__ void k_bn1fin(const float* __restrict__ s20, const float* __restrict__ Mbuf,
                         const float* __restrict__ W1, const float* __restrict__ b1,
                         const float* __restrict__ g1, const float* __restrict__ be1,
                         float* a1, float* c1) {
    __shared__ float sM[210], ss[IND];
    int j = threadIdx.x;
    if (j < 210) sM[j] = Mbuf[j];
    if (j + 128 < 210) sM[j + 128] = Mbuf[j + 128];
    if (j < IND) ss[j] = s20[j];
    __syncthreads();
    float w[IND];
#pragma unroll
    for (int k = 0; k < IND; ++k) w[k] = W1[k * HID + j];
    float tj = 0.f;
#pragma unroll
    for (int k = 0; k < IND; ++k) tj += ss[k] * w[k];
    float q = 0.f;
    int idx = 0;
#pragma unroll
    for (int k = 0; k < IND; ++k) {
        q += sM[idx] * w[k] * w[k]; ++idx;
#pragma unroll
        for (int l = k + 1; l < IND; ++l) { q += 2.f * sM[idx] * w[k] * w[l]; ++idx; }
    }
    float bj = b1[j];
    const float Nf = (float)N_NODES;
    float mean = (tj + Nf * bj) / Nf;
    float ey2  = (q + 2.f * bj * tj + Nf * bj * bj) / Nf;
    float var  = ey2 - mean * mean;
    float aj = g1[j] / sqrtf(var + BN_EPS);
    a1[j] = aj;
    c1[j] = be1[j] - mean * aj;
}

// ---------- fused layer 1: h1s = elu(bn(inv_in*(agg20@W1)+b1)) * inv_out ----------
__global__ __launch_bounds__(256) void k_l1f(const float* __restrict__ agg20,
                                             const float* __restrict__ inv_in,
                                             const float* __restrict__ inv_out,
                                             const float* __restrict__ W1,
                                             const float* __restrict__ b1,
                                             const float* __restrict__ a1,
                                             const float* __restrict__ c1,
                                             float* __restrict__ h1s) {
    __shared__ float ws[IND * HID];   // 10 KB
    int t = threadIdx.x;
    for (int i = t * 4; i < IND * HID; i += 1024)
        *(float4*)&ws[i] = *(const float4*)&W1[i];
    __syncthreads();
    int tx = t & 15, ty = t >> 4;
    int c0 = tx * 8;
    float4 ba = *(const float4*)(b1 + c0);
    float4 bb = *(const float4*)(b1 + c0 + 4);
    float4 aa = *(const float4*)(a1 + c0);
    float4 ab = *(const float4*)(a1 + c0 + 4);
    float4 ca = *(const float4*)(c1 + c0);
    float4 cb = *(const float4*)(c1 + c0 + 4);

    int row0 = blockIdx.x * 64 + ty * 4;
    const float* xr0 = agg20 + (size_t)row0 * IND;
    const float* xr1 = xr0 + IND;
    const float* xr2 = xr1 + IND;
    const float* xr3 = xr2 + IND;
    float acc[4][8];
#pragma unroll
    for (int r = 0; r < 4; ++r)
#pragma unroll
        for (int c = 0; c < 8; ++c) acc[r][c] = 0.f;

#pragma unroll
    for (int k = 0; k < IND; k += 4) {
        float4 x0 = *(const float4*)(xr0 + k);
        float4 x1 = *(const float4*)(xr1 + k);
        float4 x2 = *(const float4*)(xr2 + k);
        float4 x3 = *(const float4*)(xr3 + k);
#pragma unroll
        for (int kk = 0; kk < 4; ++kk) {
            float4 wa = *(const float4*)&ws[(k + kk) * HID + c0];
            float4 wb = *(const float4*)&ws[(k + kk) * HID + c0 + 4];
            float xk0 = (kk == 0) ? x0.x : (kk == 1) ? x0.y : (kk == 2) ? x0.z : x0.w;
            float xk1 = (kk == 0) ? x1.x : (kk == 1) ? x1.y : (kk == 2) ? x1.z : x1.w;
            float xk2 = (kk == 0) ? x2.x : (kk == 1) ? x2.y : (kk == 2) ? x2.z : x2.w;
            float xk3 = (kk == 0) ? x3.x : (kk == 1) ? x3.y : (kk == 2) ? x3.z : x3.w;
            acc[0][0] += xk0 * wa.x; acc[0][1] += xk0 * wa.y;
            acc[0][2] += xk0 * wa.z; acc[0][3] += xk0 * wa.w;
            acc[0][4] += xk0 * wb.x; acc[0][5] += xk0 * wb.y;
            acc[0][6] += xk0 * wb.z; acc[0][7] += xk0 * wb.w;
            acc[1][0] += xk1 * wa.x; acc[1][1] += xk1 * wa.y;
            acc[1][2] += xk1 * wa.z; acc[1][3] += xk1 * wa.w;
            acc[1][4] += xk1 * wb.x; acc[1][5] += xk1 * wb.y;
            acc[1][6] += xk1 * wb.z; acc[1][7] += xk1 * wb.w;
            acc[2][0] += xk2 * wa.x; acc[2][1] += xk2 * wa.y;
            acc[2][2] += xk2 * wa.z; acc[2][3] += xk2 * wa.w;
            acc[2][4] += xk2 * wb.x; acc[2][5] += xk2 * wb.y;
            acc[2][6] += xk2 * wb.z; acc[2][7] += xk2 * wb.w;
            acc[3][0] += xk3 * wa.x; acc[3][1] += xk3 * wa.y;
            acc[3][2] += xk3 * wa.z; acc[3][3] += xk3 * wa.w;
            acc[3][4] += xk3 * wb.x; acc[3][5] += xk3 * wb.y;
            acc[3][6] += xk3 * wb.z; acc[3][7] += xk3 * wb.w;
        }
    }
    float4 iv = *(const float4*)(inv_in + row0);
    float4 ov = *(const float4*)(inv_out + row0);
#pragma unroll
    for (int r = 0; r < 4; ++r) {
        float ivr = (r == 0) ? iv.x : (r == 1) ? iv.y : (r == 2) ? iv.z : iv.w;
        float ovr = (r == 0) ? ov.x : (r == 1) ? ov.y : (r == 2) ? ov.z : ov.w;
        float y[8];
        y[0] = acc[r][0] * ivr + ba.x; y[1] = acc[r][1] * ivr + ba.y;
        y[2] = acc[r][2] * ivr + ba.z; y[3] = acc[r][3] * ivr + ba.w;
        y[4] = acc[r][4] * ivr + bb.x; y[5] = acc[r][5] * ivr + bb.y;
        y[6] = acc[r][6] * ivr + bb.z; y[7] = acc[r][7] * ivr + bb.w;
        float z[8];
        z[0] = y[0] * aa.x + ca.x; z[1] = y[1] * aa.y + ca.y;
        z[2] = y[2] * aa.z + ca.z; z[3] = y[3] * aa.w + ca.w;
        z[4] = y[4] * ab.x + cb.x; z[5] = y[5] * ab.y + cb.y;
        z[6] = y[6] * ab.z + cb.z; z[7] = y[7] * ab.w + cb.w;
#pragma unroll
        for (int c = 0; c < 8; ++c) {
            float h = z[c] > 0.f ? z[c] : expm1f(z[c]);
            z[c] = h * ovr;
        }
        float* yr = h1s + (size_t)(row0 + r) * HID + c0;
        *(float4*)yr = make_float4(z[0], z[1], z[2], z[3]);
        *(float4*)(yr + 4) = make_float4(z[4], z[5], z[6], z[7]);
    }
}

// ---------- layer-2 aggregation v6: entry-list gather (no A scan) ----------
__global__ __launch_bounds__(512) void k_agg2v6(const unsigned int* __restrict__ ent,
                                                const int* __restrict__ goff,
                                                const float* __restrict__ h1s,
                                                float* __restrict__ agg2) {
    __shared__ float sh[NPG * HID];   // 51.2 KB -> 3 blocks/CU
    __shared__ int s_off[NPG + 1];
    int t = threadIdx.x;
    int g = blockIdx.x;
    int gbase = g * NPG;

    const float4* srcp = (const float4*)(h1s + (size_t)gbase * HID);
    float4* shp = (float4*)sh;
    for (int i = t; i < (NPG * HID) / 4; i += 512)
        shp[i] = srcp[i];
    if (t <= NPG) s_off[t] = goff[g * 104 + t];
    __syncthreads();

    int wv = t >> 6, lane = t & 63;
    const unsigned int* ep = ent + (size_t)g * ENT_CAP;
    for (int r = wv; r < NPG; r += 8) {
        int e0 = s_off[r], e1 = s_off[r + 1];
        float ax = 0.f, ay = 0.f;
        int i = e0;
        for (; i + 8 <= e1; i += 8) {
            unsigned int ee[8];
#pragma unroll
            for (int j = 0; j < 8; ++j) ee[j] = ep[i + j];   // independent burst
#pragma unroll
            for (int j = 0; j < 8; ++j) {
                float f = (float)(ee[j] & 255u);
                int s = ee[j] >> 8;
                float2 v = *(const float2*)&sh[s * HID + lane * 2];
                ax += f * v.x; ay += f * v.y;
            }
        }
        for (; i < e1; ++i) {
            unsigned int e = ep[i];
            float f = (float)(e & 255u);
            int s = e >> 8;
            float2 v = *(const float2*)&sh[s * HID + lane * 2];
            ax += f * v.x; ay += f * v.y;
        }
        *(float2*)(agg2 + (size_t)(gbase + r) * HID + lane * 2) = make_float2(ax, ay);
    }
}

// ---------- BN finalize (layers 2,3) ----------
__global__ void k_bnfin(const float* sums, const float* sqs,
                        const float* gamma, const float* beta,
                        float cnt, float* a, float* c) {
    int j = threadIdx.x;
    float mu  = sums[j] / cnt;
    float var = sqs[j] / cnt - mu * mu;
    float aj  = gamma[j] / sqrtf(var + BN_EPS);
    a[j] = aj;
    c[j] = beta[j] - mu * aj;
}

// ---------- layer 2 GEMM v5: split-N (2 col-halves), 32KB LDS (fp32, proven) ----------
__global__ __launch_bounds__(512) void k_l2v5(const float* __restrict__ xin,
                                              const float* __restrict__ inv_in,
                                              const float* __restrict__ W,
                                              const float* __restrict__ bvec,
                                              float* __restrict__ yout,
                                              float* sums, float* sqs) {
    __shared__ float ws[HID * 64];   // 32 KB
    int t = threadIdx.x;
    int tile = blockIdx.x >> 1;
    int half = blockIdx.x & 1;
    int cbase = half * 64;
    for (int i = t; i < HID * 16; i += 512) {       // 2048 float4s
        int k = i >> 4;
        int c4 = (i & 15) << 2;
        *(float4*)&ws[k * 64 + c4] = *(const float4*)&W[k * HID + cbase + c4];
    }
    __syncthreads();

    int tx = t & 15;
    int ty = t >> 4;
    int c0 = tx * 4;
    float4 ba = *(const float4*)(bvec + cbase + c0);
    float csum[4], csq[4];
#pragma unroll
    for (int c = 0; c < 4; ++c) { csum[c] = 0.f; csq[c] = 0.f; }

    int row0 = tile * 128 + ty * 4;
    const float* xr0 = xin + (size_t)row0 * HID;
    const float* xr1 = xr0 + HID;
    const float* xr2 = xr1 + HID;
    const float* xr3 = xr2 + HID;
    float acc[4][4];
#pragma unroll
    for (int r = 0; r < 4; ++r)
#pragma unroll
        for (int c = 0; c < 4; ++c) acc[r][c] = 0.f;

#pragma unroll 4
    for (int k = 0; k < HID; k += 4) {
        float4 x0 = *(const float4*)(xr0 + k);
        float4 x1 = *(const float4*)(xr1 + k);
        float4 x2 = *(const float4*)(xr2 + k);
        float4 x3 = *(const float4*)(xr3 + k);
#pragma unroll
        for (int kk = 0; kk < 4; ++kk) {
            float4 wa = *(const float4*)&ws[(k + kk) * 64 + c0];
            float xk0 = (kk == 0) ? x0.x : (kk == 1) ? x0.y : (kk == 2) ? x0.z : x0.w;
            float xk1 = (kk == 0) ? x1.x : (kk == 1) ? x1.y : (kk == 2) ? x1.z : x1.w;
            float xk2 = (kk == 0) ? x2.x : (kk == 1) ? x2.y : (kk == 2) ? x2.z : x2.w;
            float xk3 = (kk == 0) ? x3.x : (kk == 1) ? x3.y : (kk == 2) ? x3.z : x3.w;
            acc[0][0] += xk0 * wa.x; acc[0][1] += xk0 * wa.y;
            acc[0][2] += xk0 * wa.z; acc[0][3] += xk0 * wa.w;
            acc[1][0] += xk1 * wa.x; acc[1][1] += xk1 * wa.y;
            acc[1][2] += xk1 * wa.z; acc[1][3] += xk1 * wa.w;
            acc[2][0] += xk2 * wa.x; acc[2][1] += xk2 * wa.y;
            acc[2][2] += xk2 * wa.z; acc[2][3] += xk2 * wa.w;
            acc[3][0] += xk3 * wa.x; acc[3][1] += xk3 * wa.y;
            acc[3][2] += xk3 * wa.z; acc[3][3] += xk3 * wa.w;
        }
    }
    float4 iv = *(const float4*)(inv_in + row0);
#pragma unroll
    for (int r = 0; r < 4; ++r) {
        float ivr = (r == 0) ? iv.x : (r == 1) ? iv.y : (r == 2) ? iv.z : iv.w;
        float y0 = acc[r][0] * ivr + ba.x;
        float y1 = acc[r][1] * ivr + ba.y;
        float y2 = acc[r][2] * ivr + ba.z;
        float y3 = acc[r][3] * ivr + ba.w;
        csum[0] += y0; csq[0] += y0 * y0;
        csum[1] += y1; csq[1] += y1 * y1;
        csum[2] += y2; csq[2] += y2 * y2;
        csum[3] += y3; csq[3] += y3 * y3;
        *(float4*)(yout + (size_t)(row0 + r) * HID + cbase + c0) = make_float4(y0, y1, y2, y3);
    }

    __syncthreads();
#pragma unroll
    for (int c = 0; c < 4; ++c) {
        ws[ty * 64 + c0 + c] = csum[c];
        ws[2048 + ty * 64 + c0 + c] = csq[c];
    }
    __syncthreads();
    if (t < 64) {
        float s1 = 0.f, s2 = 0.f;
#pragma unroll
        for (int r = 0; r < 32; ++r) {
            s1 += ws[r * 64 + t];
            s2 += ws[2048 + r * 64 + t];
        }
        atomicAdd(&sums[cbase + t], s1);
        atomicAdd(&sqs[cbase + t], s2);
    }
}

// ---------- fused post: BN2+ELU in LDS + p + dvec (entry list) + pooling ----------
__global__ __launch_bounds__(512) void k_post(const unsigned int* __restrict__ ent,
                                              const int* __restrict__ goff,
                                              const float* __restrict__ y2,
                                              const float* __restrict__ a2,
                                              const float* __restrict__ c2,
                                              const float* __restrict__ inv_in,
                                              const float* __restrict__ inv_out,
                                              const float* __restrict__ Wv,
                                              const float* __restrict__ bv,
                                              float* __restrict__ vec,
                                              float* meansum) {
    __shared__ float sh[NPG * HID];
    __shared__ float s_p[NPG];
    __shared__ float s_d[NPG];
    __shared__ float s_red[512];
    __shared__ int s_off[NPG + 1];
    int t = threadIdx.x;
    int g = blockIdx.x, gbase = g * NPG;

    const float4* srcp = (const float4*)(y2 + (size_t)gbase * HID);
    for (int i = t; i < (NPG * HID) / 4; i += 512) {
        int col = (i * 4) & (HID - 1);
        float4 v = srcp[i];
        float4 av = *(const float4*)(a2 + col);
        float4 cv = *(const float4*)(c2 + col);
        float z0 = v.x * av.x + cv.x; z0 = z0 > 0.f ? z0 : expm1f(z0);
        float z1 = v.y * av.y + cv.y; z1 = z1 > 0.f ? z1 : expm1f(z1);
        float z2 = v.z * av.z + cv.z; z2 = z2 > 0.f ? z2 : expm1f(z2);
        float z3 = v.w * av.w + cv.w; z3 = z3 > 0.f ? z3 : expm1f(z3);
        *(float4*)&sh[i * 4] = make_float4(z0, z1, z2, z3);
    }
    if (t <= NPG) s_off[t] = goff[g * 104 + t];
    __syncthreads();

    int wv = t >> 6, lane = t & 63;
    float2 wvv = *(const float2*)(Wv + lane * 2);
    for (int r = wv; r < NPG; r += 8) {
        float2 h = *(const float2*)&sh[r * HID + lane * 2];
        float d = h.x * wvv.x + h.y * wvv.y;
        for (int off = 32; off; off >>= 1) d += __shfl_down(d, off);
        if (lane == 0) s_p[r] = d * inv_out[gbase + r];
    }
    __syncthreads();

    if (t < NPG) {
        const unsigned int* ep = ent + (size_t)g * ENT_CAP;
        int e0 = s_off[t], e1 = s_off[t + 1];
        float acc = 0.f;
        for (int i = e0; i < e1; ++i) {
            unsigned int e = ep[i];
            acc += (float)(e & 255u) * s_p[e >> 8];
        }
        s_d[t] = acc * inv_in[gbase + t] + bv[0];
    }
    __syncthreads();

    int col = t & (HID - 1);
    int qr = t >> 7;
    float part = 0.f;
    for (int r = qr * 25; r < qr * 25 + 25; ++r)
        part += s_d[r] * sh[r * HID + col];
    s_red[qr * HID + col] = part;
    __syncthreads();
    if (t < HID) {
        float v = s_red[t] + s_red[HID + t] + s_red[2 * HID + t] + s_red[3 * HID + t];
        vec[g * HID + t] = v;
        for (int off = 32; off; off >>= 1) v += __shfl_down(v, off);
        if ((t & 63) == 0) atomicAdd(meansum, v);
    }
}

// shrink+tanh then y3 = hg0 @ Wg + bg, fused BN stats
__global__ __launch_bounds__(128) void k_g1(const float* __restrict__ vec,
                                            const float* __restrict__ meansum,
                                            const float* __restrict__ Wg,
                                            const float* __restrict__ bg,
                                            float* y3, float* sums, float* sqs) {
    __shared__ float ws[HID * HID];
    __shared__ float rows[HID];
    int g = blockIdx.x, j = threadIdx.x;
    for (int k = 0; k < HID; ++k) ws[k * HID + j] = Wg[k * HID + j];
    float mean = meansum[0] * (1.f / (B_GR * HID));
    float v = vec[g * HID + j];
    float sh = fmaxf(v - mean, 0.f) - fmaxf(-v - mean, 0.f);
    rows[j] = tanhf(sh);
    __syncthreads();
    float acc = 0.f;
#pragma unroll 8
    for (int k = 0; k < HID; ++k) acc += rows[k] * ws[k * HID + j];
    float y = acc + bg[j];
    y3[g * HID + j] = y;
    atomicAdd(&sums[j], y);
    atomicAdd(&sqs[j], y * y);
}

// final: hg = tanh(bn(y3)), out = tanh(hg @ Wc + bc)
__global__ __launch_bounds__(128) void k_out(const float* __restrict__ y3,
                                             const float* __restrict__ a,
                                             const float* __restrict__ c,
                                             const float* __restrict__ Wc,
                                             const float* __restrict__ bc,
                                             float* out) {
    __shared__ float hg[HID];
    int g = blockIdx.x, j = threadIdx.x;
    hg[j] = tanhf(y3[g * HID + j] * a[j] + c[j]);
    __syncthreads();
    if (j < NC) {
        float acc = 0.f;
        for (int k = 0; k < HID; ++k) acc += hg[k] * Wc[k * NC + j];
        out[g * NC + j] = tanhf(acc + bc[j]);
    }
}

extern "C" void kernel_launch(void* const* d_in, const int* in_sizes, int n_in,
                              void* d_out, int out_size, void* d_ws, size_t ws_size,
                              hipStream_t stream) {
    const int*   src = (const int*)d_in[0];
    const int*   dst = (const int*)d_in[1];
    const float* W1  = (const float*)d_in[3];
    const float* b1  = (const float*)d_in[4];
    const float* g1  = (const float*)d_in[5];
    const float* be1 = (const float*)d_in[6];
    const float* W2  = (const float*)d_in[7];
    const float* b2  = (const float*)d_in[8];
    const float* g2  = (const float*)d_in[9];
    const float* be2 = (const float*)d_in[10];
    const float* Wv  = (const float*)d_in[11];
    const float* bv  = (const float*)d_in[12];
    const float* Wg  = (const float*)d_in[15];
    const float* bg  = (const float*)d_in[16];
    const float* g3  = (const float*)d_in[17];
    const float* be3 = (const float*)d_in[18];
    const float* Wc  = (const float*)d_in[19];
    const float* bc  = (const float*)d_in[20];
    float* out = (float*)d_out;

    char* ws = (char*)d_ws;
    size_t off = 0;
    auto carve = [&](size_t bytes) -> char* {
        char* pp = ws + off;
        off = (off + bytes + 255) & ~(size_t)255;
        return pp;
    };
    // ---- zeroed region ----
    unsigned int* A = (unsigned int*)carve((size_t)B_GR * NPG * NPG);  // 8 MB
    float* stats   = (float*)carve(2048 * 4);
    size_t zbytes = off;
    // ---- fully-overwritten region ----
    float* inv_in  = (float*)carve(N_NODES * 4);
    float* inv_out = (float*)carve(N_NODES * 4);
    float* vec     = (float*)carve((size_t)B_GR * HID * 4);
    float* y3      = (float*)carve((size_t)B_GR * HID * 4);
    float* agg20   = (float*)carve((size_t)N_NODES * IND * 4);
    float* bufA    = (float*)carve((size_t)N_NODES * HID * 4);   // h1s -> y2
    float* bufB    = (float*)carve((size_t)N_NODES * HID * 4);   // agg2
    unsigned int* ent = (unsigned int*)carve((size_t)B_GR * ENT_CAP * 4);
    int* goff      = (int*)carve((size_t)B_GR * 104 * 4);

    float* sums2 = stats + 0;    float* sq2 = stats + 128;
    float* a2    = stats + 256;  float* c2  = stats + 384;
    float* sums3 = stats + 512;  float* sq3 = stats + 640;
    float* a3    = stats + 768;  float* c3  = stats + 896;
    float* meansum = stats + 1024;
    float* s20   = stats + 1056;
    float* Mbuf  = stats + 1088;
    float* a1    = stats + 1312;
    float* c1    = stats + 1440;

    hipMemsetAsync(d_ws, 0, zbytes, stream);

    // single edge pass: adjacency only (1 atomic/edge)
    k_A<<<(N_EDGES + 255) / 256, 256, 0, stream>>>(src, dst, A);
    // per-graph: degrees + inv + agg20 + compact entry list
    k_prep<<<B_GR, 128, 0, stream>>>(A, inv_in, inv_out, agg20, ent, goff);
    // BN1 via moments, then fused layer-1 pass
    k_mom<<<320, 256, 0, stream>>>(agg20, inv_in, s20, Mbuf);
    k_bn1fin<<<1, 128, 0, stream>>>(s20, Mbuf, W1, b1, g1, be1, a1, c1);
    k_l1f<<<N_NODES / 64, 256, 0, stream>>>(agg20, inv_in, inv_out, W1, b1, a1, c1, bufA);
    // layer-2 aggregation: entry-list gather from LDS h1
    k_agg2v6<<<B_GR, 512, 0, stream>>>(ent, goff, bufA, bufB);
    // layer 2 GEMM (fp32, proven)
    k_l2v5<<<(N_NODES / 128) * 2, 512, 0, stream>>>(bufB, inv_in, W2, b2, bufA, sums2, sq2);
    k_bnfin<<<1, 128, 0, stream>>>(sums2, sq2, g2, be2, (float)N_NODES, a2, c2);
    // fused BN2+ELU+p+dvec+pooling
    k_post<<<B_GR, 512, 0, stream>>>(ent, goff, bufA, a2, c2, inv_in, inv_out, Wv, bv,
                                     vec, meansum);
    // graph head
    k_g1<<<B_GR, 128, 0, stream>>>(vec, meansum, Wg, bg, y3, sums3, sq3);
    k_bnfin<<<1, 128, 0, stream>>>(sums3, sq3, g3, be3, (float)B_GR, a3, c3);
    k_out<<<B_GR, 128, 0, stream>>>(y3, a3, c3, Wc, bc, out);
}